// Round 4
// baseline (109.660 us; speedup 1.0000x reference)
//
#include <hip/hip_runtime.h>

// YOLO loss: out,label [32768,17,7,7] f32 -> scalar f32.
// Flat float4 streaming. Per element flat idx: b=idx/833, r=idx%833.
// contrib = (a + bw*m) * d2, m = label[b*833 + moff], where the 836-entry
// LDS LUT gives (a,bw) as packed bf16 and moff(+sqrt flag in bit31):
//   r==0 mod-channel c=0 : a=.5 bw=.5, moff=cell           (m is l itself)
//   c in 1..4            : a=0  bw=5,  moff=cell, sqrt if c in {3,4}
//   c >= 5               : a=0  bw=1,  moff=cell
//   r in [833,836) (wrap into ch0 of batch b+1): a=.5 bw=.5, moff=r
//     (mask index = (b+1)*833 + (r-833) = b*833 + r).
// d2 = (l-o)^2, or l+o-2*sqrt(l*o) == (sqrt l - sqrt o)^2 for sqrt channels
// (one raw v_sqrt_f32 per element). Sum / (32768*49).
// Single kernel: last block (device-fence + counter) reduces the per-block
// partials in fixed index order -> bitwise deterministic.

#define BPC   833
#define CELLS 49
#define NTOT  (32768 * BPC)   // 27,295,744 floats per tensor
#define N4    (NTOT / 4)      // 6,823,936 float4s
#define NBLK  2040            // partials (8160 B) + counter (4 B) fit 8 KB ws

__global__ __launch_bounds__(256) void yolo_loss(const float* __restrict__ outp,
                                                 const float* __restrict__ lab,
                                                 float* __restrict__ partial,
                                                 unsigned* __restrict__ ctr,
                                                 float* __restrict__ res) {
    __shared__ unsigned lutW[836];   // (bf16 a)<<16 | (bf16 bw)   [exact values]
    __shared__ unsigned lutO[836];   // mask offset | (sqrt? bit31)
    for (int r = threadIdx.x; r < 836; r += 256) {
        unsigned w, o;
        if (r >= 833) {                       // wrap: ch0 of next batch
            w = (0x3F00u << 16) | 0x3F00u;    // a=0.5, bw=0.5
            o = (unsigned)r;
        } else {
            const int c    = r / CELLS;
            const int cell = r - c * CELLS;
            if (c == 0)      w = (0x3F00u << 16) | 0x3F00u;  // a=.5, bw=.5
            else if (c <= 4) w = 0x40A0u;                    // a=0,  bw=5
            else             w = 0x3F80u;                    // a=0,  bw=1
            o = (unsigned)cell | ((c == 3 || c == 4) ? 0x80000000u : 0u);
        }
        lutW[r] = w;
        lutO[r] = o;
    }
    __syncthreads();

    const int tid    = blockIdx.x * 256 + threadIdx.x;
    const int stride = gridDim.x * 256;
    float acc = 0.0f;

    for (int i4 = tid; i4 < N4; i4 += stride) {
        const float4 o4 = reinterpret_cast<const float4*>(outp)[i4];
        const float4 l4 = reinterpret_cast<const float4*>(lab)[i4];
        const float ov[4] = {o4.x, o4.y, o4.z, o4.w};
        const float lv[4] = {l4.x, l4.y, l4.z, l4.w};

        const unsigned idx   = (unsigned)i4 * 4u;
        const unsigned b     = idx / 833u;      // one magic-div per float4
        const unsigned bbase = b * 833u;
        const unsigned r0    = idx - bbase;     // 0..832

#pragma unroll
        for (int j = 0; j < 4; ++j) {
            const unsigned wp = lutW[r0 + j];
            const unsigned op = lutO[r0 + j];
            const float a  = __uint_as_float(wp & 0xFFFF0000u);
            const float bw = __uint_as_float(wp << 16);
            const float m  = lab[bbase + (op & 0x3FFu)];        // L1-hot
            const float l1 = lv[j], o1 = ov[j];
            const float dl  = l1 - o1;
            const float dl2 = dl * dl;
            const float q2  = (l1 + o1) - 2.0f * __builtin_amdgcn_sqrtf(l1 * o1);
            const float d2  = ((int)op < 0) ? q2 : dl2;
            acc = fmaf(fmaf(bw, m, a), d2, acc);
        }
    }

    // wave64 shuffle reduce
#pragma unroll
    for (int off = 32; off > 0; off >>= 1)
        acc += __shfl_down(acc, off, 64);

    __shared__ float wsum[4];
    const int lane = threadIdx.x & 63;
    const int wid  = threadIdx.x >> 6;
    if (lane == 0) wsum[wid] = acc;
    __syncthreads();

    __shared__ int isLast;
    if (threadIdx.x == 0) {
        partial[blockIdx.x] = wsum[0] + wsum[1] + wsum[2] + wsum[3];
        __threadfence();                               // publish partial
        isLast = (atomicAdd(ctr, 1u) == (unsigned)(gridDim.x - 1));
    }
    __syncthreads();

    if (isLast) {
        __threadfence();                               // acquire all partials
        float s = 0.0f;
        for (int i = threadIdx.x; i < NBLK; i += 256)  // fixed order -> deterministic
            s += partial[i];
#pragma unroll
        for (int off = 32; off > 0; off >>= 1)
            s += __shfl_down(s, off, 64);
        if (lane == 0) wsum[wid] = s;
        __syncthreads();
        if (threadIdx.x == 0)
            res[0] = (wsum[0] + wsum[1] + wsum[2] + wsum[3]) * (1.0f / 1605632.0f);
    }
}

extern "C" void kernel_launch(void* const* d_in, const int* in_sizes, int n_in,
                              void* d_out, int out_size, void* d_ws, size_t ws_size,
                              hipStream_t stream) {
    const float* outp = (const float*)d_in[0];
    const float* lab  = (const float*)d_in[1];
    float* partial    = (float*)d_ws;                    // NBLK floats
    unsigned* ctr     = (unsigned*)((char*)d_ws + NBLK * sizeof(float));
    float* res        = (float*)d_out;

    hipMemsetAsync(ctr, 0, sizeof(unsigned), stream);    // graph-capturable
    yolo_loss<<<NBLK, 256, 0, stream>>>(outp, lab, partial, ctr, res);
}

// Round 5
// 38.405 us; speedup vs baseline: 2.8553x; 2.8553x over previous
//
#include <hip/hip_runtime.h>

// YOLO loss: out,label [32768,17,7,7] f32 -> scalar f32.
// Layout view: [B, 17 channels, 49 cells]. One BATCH per WAVE, lane = cell
// (lanes 49..63 clamp to cell 48 and zero their contribution). All 34 loads
// per batch are base + c*196 with compile-time c -> coalesced constant-offset
// dword loads, no LDS, no LUT, no per-element index math. The mask is the
// channel-0 label register itself.
//   m = l0; d0 = m - o0
//   loc = sum_{c=1,2}(l-o)^2 ; siz = sum_{c=3,4}(l+o-2*sqrt(l*o)) ;
//   cls = sum_{c=5..16}(l-o)^2
//   contrib = d0^2*(0.5+0.5m) + m*(5*(loc+siz)+cls)      [m is exactly 0/1]
// Sum / (32768*49).

#define CELLS  49
#define BPC    833            // 17*49
#define NBATCH 32768
#define NBLK   2048           // 8192 waves -> 4 batches per wave

__global__ __launch_bounds__(256) void yolo_partial(const float* __restrict__ outp,
                                                    const float* __restrict__ lab,
                                                    float* __restrict__ partial) {
    const int lane   = threadIdx.x & 63;
    const int gwave  = (blockIdx.x * 256 + threadIdx.x) >> 6;   // global wave id
    const int nwaves = (NBLK * 256) >> 6;                       // 8192
    const int cell   = (lane < CELLS) ? lane : (CELLS - 1);     // clamp lanes 49..63
    const bool valid = (lane < CELLS);

    float acc = 0.0f;
    for (int b = gwave; b < NBATCH; b += nwaves) {
        const float* __restrict__ lb = lab  + b * BPC + cell;
        const float* __restrict__ ob = outp + b * BPC + cell;

        float l[17], o[17];
#pragma unroll
        for (int c = 0; c < 17; ++c) {      // constant offsets -> offset: imm
            l[c] = lb[c * CELLS];
            o[c] = ob[c * CELLS];
        }

        const float m  = l[0];              // objectness label == mask (0 or 1)
        const float d0 = m - o[0];

        float loc = 0.0f, cls = 0.0f, siz = 0.0f;
#pragma unroll
        for (int c = 1; c <= 2; ++c) { const float d = l[c] - o[c]; loc = fmaf(d, d, loc); }
#pragma unroll
        for (int c = 3; c <= 4; ++c) {      // (sqrt l - sqrt o)^2 = l+o-2*sqrt(l*o)
            const float t = l[c] + o[c];
            const float s = __builtin_amdgcn_sqrtf(l[c] * o[c]);
            siz += fmaf(-2.0f, s, t);
        }
#pragma unroll
        for (int c = 5; c < 17; ++c) { const float d = l[c] - o[c]; cls = fmaf(d, d, cls); }

        const float contrib = d0 * d0 * fmaf(0.5f, m, 0.5f)
                            + m * fmaf(5.0f, loc + siz, cls);
        acc += valid ? contrib : 0.0f;
    }

    // wave64 shuffle reduce
#pragma unroll
    for (int off = 32; off > 0; off >>= 1)
        acc += __shfl_down(acc, off, 64);

    __shared__ float wsum[4];
    const int wid = threadIdx.x >> 6;
    if (lane == 0) wsum[wid] = acc;
    __syncthreads();
    if (threadIdx.x == 0)
        partial[blockIdx.x] = wsum[0] + wsum[1] + wsum[2] + wsum[3];
}

__global__ __launch_bounds__(256) void yolo_final(const float* __restrict__ partial,
                                                  float* __restrict__ outv) {
    float acc = 0.0f;
    for (int i = threadIdx.x; i < NBLK; i += 256) acc += partial[i];
#pragma unroll
    for (int off = 32; off > 0; off >>= 1)
        acc += __shfl_down(acc, off, 64);

    __shared__ float wsum[4];
    const int lane = threadIdx.x & 63;
    const int wid  = threadIdx.x >> 6;
    if (lane == 0) wsum[wid] = acc;
    __syncthreads();
    if (threadIdx.x == 0)
        outv[0] = (wsum[0] + wsum[1] + wsum[2] + wsum[3]) * (1.0f / 1605632.0f);
}

extern "C" void kernel_launch(void* const* d_in, const int* in_sizes, int n_in,
                              void* d_out, int out_size, void* d_ws, size_t ws_size,
                              hipStream_t stream) {
    const float* outp = (const float*)d_in[0];
    const float* lab  = (const float*)d_in[1];
    float* partial    = (float*)d_ws;          // NBLK floats (8 KB)
    float* res        = (float*)d_out;

    yolo_partial<<<NBLK, 256, 0, stream>>>(outp, lab, partial);
    yolo_final<<<1, 256, 0, stream>>>(partial, res);
}